// Round 13
// baseline (269.870 us; speedup 1.0000x reference)
//
#include <hip/hip_runtime.h>
#include <hip/hip_bf16.h>

typedef _Float16 f16_t;
typedef _Float16 f16x2 __attribute__((ext_vector_type(2)));
typedef _Float16 f16x4 __attribute__((ext_vector_type(4)));
typedef _Float16 f16x8 __attribute__((ext_vector_type(8)));
typedef float f32x4 __attribute__((ext_vector_type(4)));

#define GLOAD_LDS16(gp, lp)                                                        \
  __builtin_amdgcn_global_load_lds(                                                \
      (const __attribute__((address_space(1))) void*)(gp),                         \
      (__attribute__((address_space(3))) void*)(lp), 16, 0, 0)

template<int N> __device__ __forceinline__ void vmwait() {
    if constexpr (N == 0)      asm volatile("s_waitcnt vmcnt(0)" ::: "memory");
    else if constexpr (N == 3) asm volatile("s_waitcnt vmcnt(3)" ::: "memory");
    else if constexpr (N == 5) asm volatile("s_waitcnt vmcnt(5)" ::: "memory");
    else                       asm volatile("s_waitcnt vmcnt(0)" ::: "memory");
}

// ---------------- f32 -> f16 elementwise convert (8 elems/thread) ----------------
__global__ __launch_bounds__(256) void conv_f16(const float* __restrict__ in,
                                                f16_t* __restrict__ out)
{
    int i = blockIdx.x * 256 + threadIdx.x;
    float4 a = *(const float4*)&in[(size_t)i * 8];
    float4 b = *(const float4*)&in[(size_t)i * 8 + 4];
    f16x8 o = {(f16_t)a.x, (f16_t)a.y, (f16_t)a.z, (f16_t)a.w,
               (f16_t)b.x, (f16_t)b.y, (f16_t)b.z, (f16_t)b.w};
    *(f16x8*)&out[(size_t)i * 8] = o;
}

// ------------- f32 [R][C] -> f16 transposed [C][R], 32x32 LDS tiles -------------
__global__ __launch_bounds__(256) void transpose_f16(const float* __restrict__ in,
                                                     f16_t* __restrict__ out,
                                                     int R, int C)
{
    __shared__ float t[32][33];
    const int tr = blockIdx.y, tc = blockIdx.x;
    const int r = threadIdx.x >> 3, c4 = (threadIdx.x & 7) * 4;
    float4 v = *(const float4*)&in[(size_t)(tr * 32 + r) * C + tc * 32 + c4];
    t[r][c4 + 0] = v.x; t[r][c4 + 1] = v.y; t[r][c4 + 2] = v.z; t[r][c4 + 3] = v.w;
    __syncthreads();
    f16x4 o = {(f16_t)t[c4 + 0][r], (f16_t)t[c4 + 1][r],
               (f16_t)t[c4 + 2][r], (f16_t)t[c4 + 3][r]};
    *(f16x4*)&out[(size_t)(tc * 32 + r) * R + tr * 32 + c4] = o;
}

// ------------- f16 MFMA GEMM (round-8 v6, verified 101 us) -------------
template<int BM, int BN, int GY, int F16OUT>
__global__ __launch_bounds__(512, 2) void gemm_v4(const f16_t* __restrict__ A,
                                                  const f16_t* __restrict__ BT,
                                                  void* __restrict__ Cout,
                                                  int M, int N, int K)
{
    extern __shared__ char smem[];
    constexpr int WMT = BM / 2, WNT = BN / 4;
    constexpr int MF = WMT / 16, NF = WNT / 16, MFH = MF / 2, NFH = NF / 2;
    constexpr int ALI = BM / 128, BLI = BN / 128;
    constexpr int L = ALI + BLI;
    constexpr int ABUFB = BM * 64, BBUFB = BN * 64;

    const int tid = threadIdx.x, lane = tid & 63, wave = tid >> 6;
    const int lh = lane >> 4, li = lane & 15;
    const int wr = wave >> 2, wc = wave & 3;

    const int nwg = gridDim.x, bid = blockIdx.x;
    const int swz = (bid & 7) * (nwg >> 3) + (bid >> 3);
    const int by = swz % GY, bx = swz / GY;

    const size_t bmK = (size_t)(by * BM) * K;
    const size_t bnK = (size_t)(bx * BN) * K;
    const int NT = K >> 5;

    f32x4 acc[MF][NF];
#pragma unroll
    for (int i = 0; i < MF; ++i)
#pragma unroll
        for (int j = 0; j < NF; ++j) acc[i][j] = (f32x4){0.f, 0.f, 0.f, 0.f};

#define STAGE(t, b)                                                                \
    do {                                                                           \
        const int kof_ = (t) << 5;                                                 \
        char* Ab_ = smem + (b) * ABUFB;                                            \
        char* Bb_ = smem + 3 * ABUFB + (b) * BBUFB;                                \
        _Pragma("unroll")                                                          \
        for (int i_ = 0; i_ < ALI; ++i_) {                                         \
            const int c_ = i_ * 512 + tid;                                         \
            const int row_ = c_ >> 2;                                              \
            const int gu_ = (c_ & 3) ^ ((row_ >> 1) & 3);                          \
            GLOAD_LDS16(A + bmK + (size_t)row_ * K + kof_ + gu_ * 8,               \
                        Ab_ + (i_ * 512 + wave * 64) * 16);                        \
        }                                                                          \
        _Pragma("unroll")                                                          \
        for (int i_ = 0; i_ < BLI; ++i_) {                                         \
            const int c_ = i_ * 512 + tid;                                         \
            const int row_ = c_ >> 2;                                              \
            const int gu_ = (c_ & 3) ^ ((row_ >> 1) & 3);                          \
            GLOAD_LDS16(BT + bnK + (size_t)row_ * K + kof_ + gu_ * 8,              \
                        Bb_ + (i_ * 512 + wave * 64) * 16);                        \
        }                                                                          \
    } while (0)

    STAGE(0, 0);
    STAGE(1, 1);

    const int runit = (lh ^ ((li >> 1) & 3)) << 3;

    int rb = 0;
    for (int t = 0; t < NT; ++t) {
        if (t + 1 < NT) vmwait<L>();
        else            vmwait<0>();
        __builtin_amdgcn_s_barrier();
        __builtin_amdgcn_sched_barrier(0);

        if (t + 2 < NT) {
            const int sb = rb ? rb - 1 : 2;  // (t+2)%3
            STAGE(t + 2, sb);
        }

        const f16_t* Ab = (const f16_t*)(smem + rb * ABUFB);
        const f16_t* Bb = (const f16_t*)(smem + 3 * ABUFB + rb * BBUFB);

        f16x8 af[2][MFH], bf[NFH];
#pragma unroll
        for (int ah = 0; ah < 2; ++ah)
#pragma unroll
            for (int j = 0; j < MFH; ++j)
                af[ah][j] = *(const f16x8*)(Ab + (wr * WMT + (ah * MFH + j) * 16 + li) * 32
                                            + runit);
#pragma unroll
        for (int j = 0; j < NFH; ++j)
            bf[j] = *(const f16x8*)(Bb + (wc * WNT + j * 16 + li) * 32 + runit);

        __builtin_amdgcn_s_setprio(1);
#pragma unroll
        for (int ah = 0; ah < 2; ++ah)
#pragma unroll
            for (int i = 0; i < MFH; ++i)
#pragma unroll
                for (int j = 0; j < NFH; ++j)
                    acc[ah * MFH + i][j] = __builtin_amdgcn_mfma_f32_16x16x32_f16(
                        af[ah][i], bf[j], acc[ah * MFH + i][j], 0, 0, 0);
        __builtin_amdgcn_s_setprio(0);

#pragma unroll
        for (int j = 0; j < NFH; ++j)
            bf[j] = *(const f16x8*)(Bb + (wc * WNT + (NFH + j) * 16 + li) * 32 + runit);

        __builtin_amdgcn_s_setprio(1);
#pragma unroll
        for (int ah = 0; ah < 2; ++ah)
#pragma unroll
            for (int i = 0; i < MFH; ++i)
#pragma unroll
                for (int j = 0; j < NFH; ++j)
                    acc[ah * MFH + i][NFH + j] = __builtin_amdgcn_mfma_f32_16x16x32_f16(
                        af[ah][i], bf[j], acc[ah * MFH + i][NFH + j], 0, 0, 0);
        __builtin_amdgcn_s_setprio(0);

        __builtin_amdgcn_sched_barrier(0);
        rb = (rb == 2) ? 0 : rb + 1;
    }
#undef STAGE

#pragma unroll
    for (int mf = 0; mf < MF; ++mf)
#pragma unroll
        for (int nf = 0; nf < NF; ++nf)
#pragma unroll
            for (int r = 0; r < 4; ++r) {
                const int row = by * BM + wr * WMT + mf * 16 + lh * 4 + r;
                const int col = bx * BN + wc * WNT + nf * 16 + li;
                if (F16OUT)
                    ((f16_t*)Cout)[(size_t)row * N + col] = (f16_t)acc[mf][nf][r];
                else
                    ((float*)Cout)[(size_t)row * N + col] = acc[mf][nf][r];
            }
}

// --------- fused RMSNorm + RoPE in-place on f16 qkv[B*S][3][16][128] ---------
__global__ __launch_bounds__(256) void rmsrope_f16(f16_t* __restrict__ qkv,
                                                   const float* __restrict__ pe,
                                                   const float* __restrict__ qs,
                                                   const float* __restrict__ qb,
                                                   const float* __restrict__ ks,
                                                   const float* __restrict__ kb)
{
    const int unit = blockIdx.x * 4 + (threadIdx.x >> 6);
    const int l = threadIdx.x & 63;
    const int bs = unit >> 5, h = (unit >> 1) & 15, comp = unit & 1;
    f16_t* base = qkv + ((size_t)bs * 3 + comp) * 2048 + h * 128;
    const float* sc = comp ? ks : qs;
    const float* bi = comp ? kb : qb;

    f16x2 u = *(const f16x2*)(base + 2 * l);
    float u0 = (float)u[0], u1 = (float)u[1];
    float ss = u0 * u0 + u1 * u1;
#pragma unroll
    for (int o = 32; o; o >>= 1) ss += __shfl_xor(ss, o);
    float inv = rsqrtf(ss * (1.f / 128.f) + 1e-6f);

    float2 scv = *(const float2*)(sc + 2 * l);
    float2 biv = *(const float2*)(bi + 2 * l);
    float a = u0 * inv * scv.x + biv.x;
    float c = u1 * inv * scv.y + biv.y;
    float4 p4 = *(const float4*)(pe + (size_t)bs * 256 + l * 4);
    f16x2 o = {(f16_t)(p4.x * a + p4.y * c), (f16_t)(p4.z * a + p4.w * c)};
    *(f16x2*)(base + 2 * l) = o;
}

// -------- flash attention (round-10 structure; ONLY change: exp2 softmax) --------
// 4 waves x 32 q-rows, KVBLK=64, 1 barrier/tile; K dbuf XOR-swizzled gload_lds;
// Vt dbuf permuted cols (2x b128 PV reads); prefetch AFTER QK^T (round-10
// position — issue-early regressed in r12). log2e folded into Q pre-scale.
__global__ __launch_bounds__(256) void attn_f16(const f16_t* __restrict__ qkv,
                                                f16_t* __restrict__ out)
{
    extern __shared__ char asmem[];
    f16_t* KlP = (f16_t*)asmem;               // [2][64*128] = 32 KB
    f16_t* VtP = (f16_t*)(asmem + 32768);     // [2][128*72] = 36 KB
    const int tid = threadIdx.x, lane = tid & 63, wave = tid >> 6;
    const int lh = lane >> 4, li = lane & 15;
    const int bidx = blockIdx.x;
    const int bh = bidx & 63;
    const int qt = bidx >> 6;
    const int h = bh & 15, b = bh >> 4;
    const size_t seqbase = (size_t)b * 1024;
    // 1/sqrt(128) * log2(e): all exps become native exp2
    const float SCALE = 0.08838834764831845f * 1.44269504088896341f;

    const int qbase = qt * 128 + wave * 32;
    f16x8 qreg[2][4];
#pragma unroll
    for (int qf = 0; qf < 2; ++qf) {
        const f16_t* qp = qkv + (seqbase + qbase + qf * 16 + li) * 6144 + h * 128;
#pragma unroll
        for (int c = 0; c < 4; ++c) {
            f16x8 v = *(const f16x8*)(qp + c * 32 + lh * 8);
#pragma unroll
            for (int j = 0; j < 8; ++j) v[j] = (f16_t)((float)v[j] * SCALE);
            qreg[qf][c] = v;
        }
    }

    f32x4 oacc[2][8];
#pragma unroll
    for (int qf = 0; qf < 2; ++qf)
#pragma unroll
        for (int dt = 0; dt < 8; ++dt) oacc[qf][dt] = (f32x4){0.f, 0.f, 0.f, 0.f};
    float mrun[2] = {-1e30f, -1e30f}, lrun[2] = {0.f, 0.f};

    const int vd0 = (tid & 31) * 4;
    const int w5 = tid >> 5;
    const int vk0 = w5 * 8;
    f16x4 vreg[8];

#define STAGE_K(t, buf)                                                            \
    do {                                                                           \
        _Pragma("unroll")                                                          \
        for (int it = 0; it < 4; ++it) {                                           \
            const int c_ = it * 256 + tid;                                         \
            const int row_ = c_ >> 4, cc_ = c_ & 15;                               \
            const f16_t* src_ = qkv + (seqbase + (t) * 64 + row_) * 6144 + 2048 +  \
                                h * 128 + ((cc_ ^ (row_ & 7)) << 3);               \
            GLOAD_LDS16(src_, (char*)KlP + (buf) * 16384 +                         \
                        (it * 256 + wave * 64) * 16);                              \
        }                                                                          \
    } while (0)

#define LOAD_V(t)                                                                  \
    do {                                                                           \
        _Pragma("unroll")                                                          \
        for (int r_ = 0; r_ < 8; ++r_)                                             \
            vreg[r_] = *(const f16x4*)(qkv + (seqbase + (t) * 64 + vk0 + r_) *     \
                                       6144 + 4096 + h * 128 + vd0);               \
    } while (0)

#define WRITE_VT(bufv)                                                             \
    do {                                                                           \
        const int u0_ = 4 * (w5 & 1) + (w5 >> 2);                                  \
        const int woff_ = 4 * ((w5 >> 1) & 1);                                     \
        _Pragma("unroll")                                                          \
        for (int dd = 0; dd < 4; ++dd) {                                           \
            const int rr_ = vd0 + dd;                                              \
            const int xr_ = (rr_ & 7) ^ ((rr_ >> 3) & 7);                          \
            f16x4 wv0 = {vreg[0][dd], vreg[1][dd], vreg[2][dd], vreg[3][dd]};      \
            f16x4 wv1 = {vreg[4][dd], vreg[5][dd], vreg[6][dd], vreg[7][dd]};      \
            f16_t* bp_ = VtP + (bufv) * 9216 + rr_ * 72;                           \
            *(f16x4*)(bp_ + ((u0_ ^ xr_) << 3) + woff_) = wv0;                     \
            *(f16x4*)(bp_ + (((u0_ + 2) ^ xr_) << 3) + woff_) = wv1;               \
        }                                                                          \
    } while (0)

    STAGE_K(0, 0);
    LOAD_V(0);
    asm volatile("s_waitcnt vmcnt(0)" ::: "memory");
    WRITE_VT(0);
    __syncthreads();

    for (int t = 0; t < 16; ++t) {
        const int buf = t & 1;

        // ---- QK^T (log2-domain scores) ----
        float s[2][16];
#pragma unroll
        for (int kvt = 0; kvt < 4; ++kvt) {
            f32x4 a0 = (f32x4){0.f, 0.f, 0.f, 0.f}, a1 = a0;
            __builtin_amdgcn_s_setprio(1);
#pragma unroll
            for (int c = 0; c < 4; ++c) {
                const int kvrow = kvt * 16 + li;
                f16x8 kf = *(const f16x8*)&KlP[buf * 8192 + kvrow * 128 +
                                               (((c * 4 + lh) ^ (li & 7)) << 3)];
                a0 = __builtin_amdgcn_mfma_f32_16x16x32_f16(kf, qreg[0][c], a0, 0, 0, 0);
                a1 = __builtin_amdgcn_mfma_f32_16x16x32_f16(kf, qreg[1][c], a1, 0, 0, 0);
            }
            __builtin_amdgcn_s_setprio(0);
#pragma unroll
            for (int r = 0; r < 4; ++r) { s[0][kvt * 4 + r] = a0[r]; s[1][kvt * 4 + r] = a1[r]; }
        }

        // ---- prefetch of tile t+1 (round-10 position: after QK^T) ----
        if (t < 15) {
            STAGE_K(t + 1, buf ^ 1);
            LOAD_V(t + 1);
        }

        // ---- online softmax (exp2) with defer-max (THR = 8*log2e ~ 11.5) ----
        float pmax[2];
#pragma unroll
        for (int qf = 0; qf < 2; ++qf) {
            float mx = s[qf][0];
#pragma unroll
            for (int i = 1; i < 16; ++i) mx = fmaxf(mx, s[qf][i]);
            mx = fmaxf(mx, __shfl_xor(mx, 16));
            mx = fmaxf(mx, __shfl_xor(mx, 32));
            pmax[qf] = mx;
        }
        const bool defer = __all((pmax[0] - mrun[0] <= 11.5f) && (pmax[1] - mrun[1] <= 11.5f));
        if (!defer) {
#pragma unroll
            for (int qf = 0; qf < 2; ++qf) {
                const float mn = fmaxf(mrun[qf], pmax[qf]);
                const float alpha = exp2f(mrun[qf] - mn);
                lrun[qf] *= alpha;
                mrun[qf] = mn;
                float ar[4];
#pragma unroll
                for (int r = 0; r < 4; ++r) ar[r] = __shfl(alpha, 4 * lh + r);
#pragma unroll
                for (int dt = 0; dt < 8; ++dt)
#pragma unroll
                    for (int r = 0; r < 4; ++r) oacc[qf][dt][r] *= ar[r];
            }
        }

        f16x8 pa[2][2];
#pragma unroll
        for (int qf = 0; qf < 2; ++qf) {
            float ls = 0.f;
            float p[16];
#pragma unroll
            for (int i = 0; i < 16; ++i) { p[i] = exp2f(s[qf][i] - mrun[qf]); ls += p[i]; }
            ls += __shfl_xor(ls, 16);
            ls += __shfl_xor(ls, 32);
            lrun[qf] += ls;
#pragma unroll
            for (int hf = 0; hf < 2; ++hf)
#pragma unroll
                for (int j = 0; j < 8; ++j)
                    pa[qf][hf][j] = (f16_t)p[(2 * hf + (j >> 2)) * 4 + (j & 3)];
        }

        // ---- PV from permuted Vt[buf]: 2x b128 per dt ----
#pragma unroll
        for (int dt = 0; dt < 8; ++dt) {
            const int drow = dt * 16 + li;
            const int xr = (drow & 7) ^ ((drow >> 3) & 7);
            const f16_t* bp = VtP + buf * 9216 + drow * 72;
            f16x8 vf0 = *(const f16x8*)(bp + (((lh * 2) ^ xr) << 3));
            f16x8 vf1 = *(const f16x8*)(bp + (((lh * 2 + 1) ^ xr) << 3));
            __builtin_amdgcn_s_setprio(1);
#pragma unroll
            for (int qf = 0; qf < 2; ++qf) {
                oacc[qf][dt] = __builtin_amdgcn_mfma_f32_16x16x32_f16(pa[qf][0], vf0,
                                                                      oacc[qf][dt], 0, 0, 0);
                oacc[qf][dt] = __builtin_amdgcn_mfma_f32_16x16x32_f16(pa[qf][1], vf1,
                                                                      oacc[qf][dt], 0, 0, 0);
            }
            __builtin_amdgcn_s_setprio(0);
        }

        // ---- land prefetch, publish Vt[(t+1)&1], single barrier ----
        if (t < 15) {
            asm volatile("s_waitcnt vmcnt(0)" ::: "memory");
            WRITE_VT(buf ^ 1);
            __syncthreads();
        }
    }

#pragma unroll
    for (int qf = 0; qf < 2; ++qf) {
        const float inv = 1.f / lrun[qf];
        float ir[4];
#pragma unroll
        for (int r = 0; r < 4; ++r) ir[r] = __shfl(inv, 4 * lh + r);
#pragma unroll
        for (int dt = 0; dt < 8; ++dt)
#pragma unroll
            for (int r = 0; r < 4; ++r) {
                const int row = qbase + qf * 16 + 4 * lh + r;
                out[(seqbase + row) * 2048 + h * 128 + dt * 16 + li] =
                    (f16_t)(oacc[qf][dt][r] * ir[r]);
            }
    }
#undef STAGE_K
#undef LOAD_V
#undef WRITE_VT
}

extern "C" void kernel_launch(void* const* d_in, const int* in_sizes, int n_in,
                              void* d_out, int out_size, void* d_ws, size_t ws_size,
                              hipStream_t stream) {
    const float* x       = (const float*)d_in[0];
    const float* pe      = (const float*)d_in[1];
    const float* w_qkv   = (const float*)d_in[2];
    const float* w_o     = (const float*)d_in[3];
    const float* q_scale = (const float*)d_in[4];
    const float* q_bias  = (const float*)d_in[5];
    const float* k_scale = (const float*)d_in[6];
    const float* k_bias  = (const float*)d_in[7];
    float* out = (float*)d_out;

    char* ws = (char*)d_ws;
    f16_t* x16    = (f16_t*)(ws);
    f16_t* wqkvT  = (f16_t*)(ws + 16777216);
    f16_t* woT    = (f16_t*)(ws + 41943040);
    f16_t* qkv16  = (f16_t*)(ws + 50331648);
    f16_t* attn16 = (f16_t*)(ws + 100663296);

    hipFuncSetAttribute((const void*)&gemm_v4<256, 384, 16, 1>,
                        hipFuncAttributeMaxDynamicSharedMemorySize, 122880);
    hipFuncSetAttribute((const void*)&gemm_v4<128, 256, 32, 0>,
                        hipFuncAttributeMaxDynamicSharedMemorySize, 73728);
    hipFuncSetAttribute((const void*)&attn_f16,
                        hipFuncAttributeMaxDynamicSharedMemorySize, 69632);

    conv_f16<<<4096, 256, 0, stream>>>(x, x16);
    transpose_f16<<<dim3(6144 / 32, 2048 / 32), 256, 0, stream>>>(w_qkv, wqkvT, 2048, 6144);
    transpose_f16<<<dim3(2048 / 32, 2048 / 32), 256, 0, stream>>>(w_o, woT, 2048, 2048);

    // qkv = x @ w_qkv: tiles 256x384, grid 16x16=256 (1 round)
    gemm_v4<256, 384, 16, 1><<<256, 512, 122880, stream>>>(x16, wqkvT, qkv16,
                                                           4096, 6144, 2048);

    rmsrope_f16<<<32768, 256, 0, stream>>>(qkv16, pe, q_scale, q_bias, k_scale, k_bias);

    // attention: 68 KB dynamic LDS, 2 blocks/CU, grid 512 = exactly 1 round
    attn_f16<<<512, 256, 69632, stream>>>(qkv16, attn16);

    // out = attn @ w_o: tiles 128x256, grid 32x8=256 (1 round)
    gemm_v4<128, 256, 32, 0><<<256, 512, 73728, stream>>>(attn16, woT, out,
                                                          4096, 2048, 2048);
}

// Round 14
// 257.204 us; speedup vs baseline: 1.0492x; 1.0492x over previous
//
#include <hip/hip_runtime.h>
#include <hip/hip_bf16.h>

typedef _Float16 f16_t;
typedef _Float16 f16x2 __attribute__((ext_vector_type(2)));
typedef _Float16 f16x4 __attribute__((ext_vector_type(4)));
typedef _Float16 f16x8 __attribute__((ext_vector_type(8)));
typedef float f32x4 __attribute__((ext_vector_type(4)));

#define GLOAD_LDS16(gp, lp)                                                        \
  __builtin_amdgcn_global_load_lds(                                                \
      (const __attribute__((address_space(1))) void*)(gp),                         \
      (__attribute__((address_space(3))) void*)(lp), 16, 0, 0)

template<int N> __device__ __forceinline__ void vmwait() {
    if constexpr (N == 0)      asm volatile("s_waitcnt vmcnt(0)" ::: "memory");
    else if constexpr (N == 3) asm volatile("s_waitcnt vmcnt(3)" ::: "memory");
    else if constexpr (N == 5) asm volatile("s_waitcnt vmcnt(5)" ::: "memory");
    else                       asm volatile("s_waitcnt vmcnt(0)" ::: "memory");
}

// ---- merged prep: x f32->f16 convert + w_qkv^T + w_o^T in ONE dispatch ----
// blocks [0,4096): conv; [4096,16384): wqkv transpose; [16384,20480): wo transpose
__global__ __launch_bounds__(256) void prep(const float* __restrict__ x,
                                            f16_t* __restrict__ x16,
                                            const float* __restrict__ w_qkv,
                                            f16_t* __restrict__ wqkvT,
                                            const float* __restrict__ w_o,
                                            f16_t* __restrict__ woT)
{
    __shared__ float t[32][33];
    const int bid = blockIdx.x;
    if (bid < 4096) {
        const int i = bid * 256 + threadIdx.x;
        float4 a = *(const float4*)&x[(size_t)i * 8];
        float4 b = *(const float4*)&x[(size_t)i * 8 + 4];
        f16x8 o = {(f16_t)a.x, (f16_t)a.y, (f16_t)a.z, (f16_t)a.w,
                   (f16_t)b.x, (f16_t)b.y, (f16_t)b.z, (f16_t)b.w};
        *(f16x8*)&x16[(size_t)i * 8] = o;
        return;
    }
    const float* in;
    f16_t* outp;
    int R, C, tr, tc;
    if (bid < 4096 + 192 * 64) {
        const int idx = bid - 4096;
        tc = idx % 192; tr = idx / 192;
        in = w_qkv; outp = wqkvT; R = 2048; C = 6144;
    } else {
        const int idx = bid - 4096 - 192 * 64;
        tc = idx % 64; tr = idx / 64;
        in = w_o; outp = woT; R = 2048; C = 2048;
    }
    const int r = threadIdx.x >> 3, c4 = (threadIdx.x & 7) * 4;
    float4 v = *(const float4*)&in[(size_t)(tr * 32 + r) * C + tc * 32 + c4];
    t[r][c4 + 0] = v.x; t[r][c4 + 1] = v.y; t[r][c4 + 2] = v.z; t[r][c4 + 3] = v.w;
    __syncthreads();
    f16x4 o = {(f16_t)t[c4 + 0][r], (f16_t)t[c4 + 1][r],
               (f16_t)t[c4 + 2][r], (f16_t)t[c4 + 3][r]};
    *(f16x4*)&outp[(size_t)(tc * 32 + r) * R + tr * 32 + c4] = o;
}

// ------------- f16 MFMA GEMM (round-8 v6, verified 101 us) -------------
template<int BM, int BN, int GY, int F16OUT>
__global__ __launch_bounds__(512, 2) void gemm_v4(const f16_t* __restrict__ A,
                                                  const f16_t* __restrict__ BT,
                                                  void* __restrict__ Cout,
                                                  int M, int N, int K)
{
    extern __shared__ char smem[];
    constexpr int WMT = BM / 2, WNT = BN / 4;
    constexpr int MF = WMT / 16, NF = WNT / 16, MFH = MF / 2, NFH = NF / 2;
    constexpr int ALI = BM / 128, BLI = BN / 128;
    constexpr int L = ALI + BLI;
    constexpr int ABUFB = BM * 64, BBUFB = BN * 64;

    const int tid = threadIdx.x, lane = tid & 63, wave = tid >> 6;
    const int lh = lane >> 4, li = lane & 15;
    const int wr = wave >> 2, wc = wave & 3;

    const int nwg = gridDim.x, bid = blockIdx.x;
    const int swz = (bid & 7) * (nwg >> 3) + (bid >> 3);
    const int by = swz % GY, bx = swz / GY;

    const size_t bmK = (size_t)(by * BM) * K;
    const size_t bnK = (size_t)(bx * BN) * K;
    const int NT = K >> 5;

    f32x4 acc[MF][NF];
#pragma unroll
    for (int i = 0; i < MF; ++i)
#pragma unroll
        for (int j = 0; j < NF; ++j) acc[i][j] = (f32x4){0.f, 0.f, 0.f, 0.f};

#define STAGE(t, b)                                                                \
    do {                                                                           \
        const int kof_ = (t) << 5;                                                 \
        char* Ab_ = smem + (b) * ABUFB;                                            \
        char* Bb_ = smem + 3 * ABUFB + (b) * BBUFB;                                \
        _Pragma("unroll")                                                          \
        for (int i_ = 0; i_ < ALI; ++i_) {                                         \
            const int c_ = i_ * 512 + tid;                                         \
            const int row_ = c_ >> 2;                                              \
            const int gu_ = (c_ & 3) ^ ((row_ >> 1) & 3);                          \
            GLOAD_LDS16(A + bmK + (size_t)row_ * K + kof_ + gu_ * 8,               \
                        Ab_ + (i_ * 512 + wave * 64) * 16);                        \
        }                                                                          \
        _Pragma("unroll")                                                          \
        for (int i_ = 0; i_ < BLI; ++i_) {                                         \
            const int c_ = i_ * 512 + tid;                                         \
            const int row_ = c_ >> 2;                                              \
            const int gu_ = (c_ & 3) ^ ((row_ >> 1) & 3);                          \
            GLOAD_LDS16(BT + bnK + (size_t)row_ * K + kof_ + gu_ * 8,              \
                        Bb_ + (i_ * 512 + wave * 64) * 16);                        \
        }                                                                          \
    } while (0)

    STAGE(0, 0);
    STAGE(1, 1);

    const int runit = (lh ^ ((li >> 1) & 3)) << 3;

    int rb = 0;
    for (int t = 0; t < NT; ++t) {
        if (t + 1 < NT) vmwait<L>();
        else            vmwait<0>();
        __builtin_amdgcn_s_barrier();
        __builtin_amdgcn_sched_barrier(0);

        if (t + 2 < NT) {
            const int sb = rb ? rb - 1 : 2;  // (t+2)%3
            STAGE(t + 2, sb);
        }

        const f16_t* Ab = (const f16_t*)(smem + rb * ABUFB);
        const f16_t* Bb = (const f16_t*)(smem + 3 * ABUFB + rb * BBUFB);

        f16x8 af[2][MFH], bf[NFH];
#pragma unroll
        for (int ah = 0; ah < 2; ++ah)
#pragma unroll
            for (int j = 0; j < MFH; ++j)
                af[ah][j] = *(const f16x8*)(Ab + (wr * WMT + (ah * MFH + j) * 16 + li) * 32
                                            + runit);
#pragma unroll
        for (int j = 0; j < NFH; ++j)
            bf[j] = *(const f16x8*)(Bb + (wc * WNT + j * 16 + li) * 32 + runit);

        __builtin_amdgcn_s_setprio(1);
#pragma unroll
        for (int ah = 0; ah < 2; ++ah)
#pragma unroll
            for (int i = 0; i < MFH; ++i)
#pragma unroll
                for (int j = 0; j < NFH; ++j)
                    acc[ah * MFH + i][j] = __builtin_amdgcn_mfma_f32_16x16x32_f16(
                        af[ah][i], bf[j], acc[ah * MFH + i][j], 0, 0, 0);
        __builtin_amdgcn_s_setprio(0);

#pragma unroll
        for (int j = 0; j < NFH; ++j)
            bf[j] = *(const f16x8*)(Bb + (wc * WNT + (NFH + j) * 16 + li) * 32 + runit);

        __builtin_amdgcn_s_setprio(1);
#pragma unroll
        for (int ah = 0; ah < 2; ++ah)
#pragma unroll
            for (int i = 0; i < MFH; ++i)
#pragma unroll
                for (int j = 0; j < NFH; ++j)
                    acc[ah * MFH + i][NFH + j] = __builtin_amdgcn_mfma_f32_16x16x32_f16(
                        af[ah][i], bf[j], acc[ah * MFH + i][NFH + j], 0, 0, 0);
        __builtin_amdgcn_s_setprio(0);

        __builtin_amdgcn_sched_barrier(0);
        rb = (rb == 2) ? 0 : rb + 1;
    }
#undef STAGE

#pragma unroll
    for (int mf = 0; mf < MF; ++mf)
#pragma unroll
        for (int nf = 0; nf < NF; ++nf)
#pragma unroll
            for (int r = 0; r < 4; ++r) {
                const int row = by * BM + wr * WMT + mf * 16 + lh * 4 + r;
                const int col = bx * BN + wc * WNT + nf * 16 + li;
                if (F16OUT)
                    ((f16_t*)Cout)[(size_t)row * N + col] = (f16_t)acc[mf][nf][r];
                else
                    ((float*)Cout)[(size_t)row * N + col] = acc[mf][nf][r];
            }
}

// --------- fused RMSNorm + RoPE in-place on f16 qkv[B*S][3][16][128] ---------
__global__ __launch_bounds__(256) void rmsrope_f16(f16_t* __restrict__ qkv,
                                                   const float* __restrict__ pe,
                                                   const float* __restrict__ qs,
                                                   const float* __restrict__ qb,
                                                   const float* __restrict__ ks,
                                                   const float* __restrict__ kb)
{
    const int unit = blockIdx.x * 4 + (threadIdx.x >> 6);
    const int l = threadIdx.x & 63;
    const int bs = unit >> 5, h = (unit >> 1) & 15, comp = unit & 1;
    f16_t* base = qkv + ((size_t)bs * 3 + comp) * 2048 + h * 128;
    const float* sc = comp ? ks : qs;
    const float* bi = comp ? kb : qb;

    f16x2 u = *(const f16x2*)(base + 2 * l);
    float u0 = (float)u[0], u1 = (float)u[1];
    float ss = u0 * u0 + u1 * u1;
#pragma unroll
    for (int o = 32; o; o >>= 1) ss += __shfl_xor(ss, o);
    float inv = rsqrtf(ss * (1.f / 128.f) + 1e-6f);

    float2 scv = *(const float2*)(sc + 2 * l);
    float2 biv = *(const float2*)(bi + 2 * l);
    float a = u0 * inv * scv.x + biv.x;
    float c = u1 * inv * scv.y + biv.y;
    float4 p4 = *(const float4*)(pe + (size_t)bs * 256 + l * 4);
    f16x2 o = {(f16_t)(p4.x * a + p4.y * c), (f16_t)(p4.z * a + p4.w * c)};
    *(f16x2*)(base + 2 * l) = o;
}

// -------- flash attention (round-10 verified): 4 waves x 32 q-rows, KVBLK=64 ----
// K dbuf XOR-swizzled gload_lds; Vt dbuf permuted cols (2x b128 PV reads);
// prefetch after QK^T; __expf softmax; defer-max THR=8; 1 barrier/tile.
__global__ __launch_bounds__(256) void attn_f16(const f16_t* __restrict__ qkv,
                                                f16_t* __restrict__ out)
{
    extern __shared__ char asmem[];
    f16_t* KlP = (f16_t*)asmem;               // [2][64*128] = 32 KB
    f16_t* VtP = (f16_t*)(asmem + 32768);     // [2][128*72] = 36 KB
    const int tid = threadIdx.x, lane = tid & 63, wave = tid >> 6;
    const int lh = lane >> 4, li = lane & 15;
    const int bidx = blockIdx.x;
    const int bh = bidx & 63;
    const int qt = bidx >> 6;
    const int h = bh & 15, b = bh >> 4;
    const size_t seqbase = (size_t)b * 1024;
    const float SCALE = 0.08838834764831845f;  // 1/sqrt(128)

    const int qbase = qt * 128 + wave * 32;
    f16x8 qreg[2][4];
#pragma unroll
    for (int qf = 0; qf < 2; ++qf) {
        const f16_t* qp = qkv + (seqbase + qbase + qf * 16 + li) * 6144 + h * 128;
#pragma unroll
        for (int c = 0; c < 4; ++c) {
            f16x8 v = *(const f16x8*)(qp + c * 32 + lh * 8);
#pragma unroll
            for (int j = 0; j < 8; ++j) v[j] = (f16_t)((float)v[j] * SCALE);
            qreg[qf][c] = v;
        }
    }

    f32x4 oacc[2][8];
#pragma unroll
    for (int qf = 0; qf < 2; ++qf)
#pragma unroll
        for (int dt = 0; dt < 8; ++dt) oacc[qf][dt] = (f32x4){0.f, 0.f, 0.f, 0.f};
    float mrun[2] = {-1e30f, -1e30f}, lrun[2] = {0.f, 0.f};

    const int vd0 = (tid & 31) * 4;
    const int w5 = tid >> 5;
    const int vk0 = w5 * 8;
    f16x4 vreg[8];

#define STAGE_K(t, buf)                                                            \
    do {                                                                           \
        _Pragma("unroll")                                                          \
        for (int it = 0; it < 4; ++it) {                                           \
            const int c_ = it * 256 + tid;                                         \
            const int row_ = c_ >> 4, cc_ = c_ & 15;                               \
            const f16_t* src_ = qkv + (seqbase + (t) * 64 + row_) * 6144 + 2048 +  \
                                h * 128 + ((cc_ ^ (row_ & 7)) << 3);               \
            GLOAD_LDS16(src_, (char*)KlP + (buf) * 16384 +                         \
                        (it * 256 + wave * 64) * 16);                              \
        }                                                                          \
    } while (0)

#define LOAD_V(t)                                                                  \
    do {                                                                           \
        _Pragma("unroll")                                                          \
        for (int r_ = 0; r_ < 8; ++r_)                                             \
            vreg[r_] = *(const f16x4*)(qkv + (seqbase + (t) * 64 + vk0 + r_) *     \
                                       6144 + 4096 + h * 128 + vd0);               \
    } while (0)

#define WRITE_VT(bufv)                                                             \
    do {                                                                           \
        const int u0_ = 4 * (w5 & 1) + (w5 >> 2);                                  \
        const int woff_ = 4 * ((w5 >> 1) & 1);                                     \
        _Pragma("unroll")                                                          \
        for (int dd = 0; dd < 4; ++dd) {                                           \
            const int rr_ = vd0 + dd;                                              \
            const int xr_ = (rr_ & 7) ^ ((rr_ >> 3) & 7);                          \
            f16x4 wv0 = {vreg[0][dd], vreg[1][dd], vreg[2][dd], vreg[3][dd]};      \
            f16x4 wv1 = {vreg[4][dd], vreg[5][dd], vreg[6][dd], vreg[7][dd]};      \
            f16_t* bp_ = VtP + (bufv) * 9216 + rr_ * 72;                           \
            *(f16x4*)(bp_ + ((u0_ ^ xr_) << 3) + woff_) = wv0;                     \
            *(f16x4*)(bp_ + (((u0_ + 2) ^ xr_) << 3) + woff_) = wv1;               \
        }                                                                          \
    } while (0)

    STAGE_K(0, 0);
    LOAD_V(0);
    asm volatile("s_waitcnt vmcnt(0)" ::: "memory");
    WRITE_VT(0);
    __syncthreads();

    for (int t = 0; t < 16; ++t) {
        const int buf = t & 1;

        // ---- QK^T from Kl[buf] ----
        float s[2][16];
#pragma unroll
        for (int kvt = 0; kvt < 4; ++kvt) {
            f32x4 a0 = (f32x4){0.f, 0.f, 0.f, 0.f}, a1 = a0;
            __builtin_amdgcn_s_setprio(1);
#pragma unroll
            for (int c = 0; c < 4; ++c) {
                const int kvrow = kvt * 16 + li;
                f16x8 kf = *(const f16x8*)&KlP[buf * 8192 + kvrow * 128 +
                                               (((c * 4 + lh) ^ (li & 7)) << 3)];
                a0 = __builtin_amdgcn_mfma_f32_16x16x32_f16(kf, qreg[0][c], a0, 0, 0, 0);
                a1 = __builtin_amdgcn_mfma_f32_16x16x32_f16(kf, qreg[1][c], a1, 0, 0, 0);
            }
            __builtin_amdgcn_s_setprio(0);
#pragma unroll
            for (int r = 0; r < 4; ++r) { s[0][kvt * 4 + r] = a0[r]; s[1][kvt * 4 + r] = a1[r]; }
        }

        // ---- prefetch of tile t+1 (hidden under softmax+PV) ----
        if (t < 15) {
            STAGE_K(t + 1, buf ^ 1);
            LOAD_V(t + 1);
        }

        // ---- online softmax with defer-max ----
        float pmax[2];
#pragma unroll
        for (int qf = 0; qf < 2; ++qf) {
            float mx = s[qf][0];
#pragma unroll
            for (int i = 1; i < 16; ++i) mx = fmaxf(mx, s[qf][i]);
            mx = fmaxf(mx, __shfl_xor(mx, 16));
            mx = fmaxf(mx, __shfl_xor(mx, 32));
            pmax[qf] = mx;
        }
        const bool defer = __all((pmax[0] - mrun[0] <= 8.f) && (pmax[1] - mrun[1] <= 8.f));
        if (!defer) {
#pragma unroll
            for (int qf = 0; qf < 2; ++qf) {
                const float mn = fmaxf(mrun[qf], pmax[qf]);
                const float alpha = __expf(mrun[qf] - mn);
                lrun[qf] *= alpha;
                mrun[qf] = mn;
                float ar[4];
#pragma unroll
                for (int r = 0; r < 4; ++r) ar[r] = __shfl(alpha, 4 * lh + r);
#pragma unroll
                for (int dt = 0; dt < 8; ++dt)
#pragma unroll
                    for (int r = 0; r < 4; ++r) oacc[qf][dt][r] *= ar[r];
            }
        }

        f16x8 pa[2][2];
#pragma unroll
        for (int qf = 0; qf < 2; ++qf) {
            float ls = 0.f;
            float p[16];
#pragma unroll
            for (int i = 0; i < 16; ++i) { p[i] = __expf(s[qf][i] - mrun[qf]); ls += p[i]; }
            ls += __shfl_xor(ls, 16);
            ls += __shfl_xor(ls, 32);
            lrun[qf] += ls;
#pragma unroll
            for (int hf = 0; hf < 2; ++hf)
#pragma unroll
                for (int j = 0; j < 8; ++j)
                    pa[qf][hf][j] = (f16_t)p[(2 * hf + (j >> 2)) * 4 + (j & 3)];
        }

        // ---- PV from permuted Vt[buf]: 2x b128 per dt ----
#pragma unroll
        for (int dt = 0; dt < 8; ++dt) {
            const int drow = dt * 16 + li;
            const int xr = (drow & 7) ^ ((drow >> 3) & 7);
            const f16_t* bp = VtP + buf * 9216 + drow * 72;
            f16x8 vf0 = *(const f16x8*)(bp + (((lh * 2) ^ xr) << 3));
            f16x8 vf1 = *(const f16x8*)(bp + (((lh * 2 + 1) ^ xr) << 3));
            __builtin_amdgcn_s_setprio(1);
#pragma unroll
            for (int qf = 0; qf < 2; ++qf) {
                oacc[qf][dt] = __builtin_amdgcn_mfma_f32_16x16x32_f16(pa[qf][0], vf0,
                                                                      oacc[qf][dt], 0, 0, 0);
                oacc[qf][dt] = __builtin_amdgcn_mfma_f32_16x16x32_f16(pa[qf][1], vf1,
                                                                      oacc[qf][dt], 0, 0, 0);
            }
            __builtin_amdgcn_s_setprio(0);
        }

        // ---- land prefetch, publish Vt[(t+1)&1], single barrier ----
        if (t < 15) {
            asm volatile("s_waitcnt vmcnt(0)" ::: "memory");
            WRITE_VT(buf ^ 1);
            __syncthreads();
        }
    }

#pragma unroll
    for (int qf = 0; qf < 2; ++qf) {
        const float inv = 1.f / lrun[qf];
        float ir[4];
#pragma unroll
        for (int r = 0; r < 4; ++r) ir[r] = __shfl(inv, 4 * lh + r);
#pragma unroll
        for (int dt = 0; dt < 8; ++dt)
#pragma unroll
            for (int r = 0; r < 4; ++r) {
                const int row = qbase + qf * 16 + 4 * lh + r;
                out[(seqbase + row) * 2048 + h * 128 + dt * 16 + li] =
                    (f16_t)(oacc[qf][dt][r] * ir[r]);
            }
    }
#undef STAGE_K
#undef LOAD_V
#undef WRITE_VT
}

extern "C" void kernel_launch(void* const* d_in, const int* in_sizes, int n_in,
                              void* d_out, int out_size, void* d_ws, size_t ws_size,
                              hipStream_t stream) {
    const float* x       = (const float*)d_in[0];
    const float* pe      = (const float*)d_in[1];
    const float* w_qkv   = (const float*)d_in[2];
    const float* w_o     = (const float*)d_in[3];
    const float* q_scale = (const float*)d_in[4];
    const float* q_bias  = (const float*)d_in[5];
    const float* k_scale = (const float*)d_in[6];
    const float* k_bias  = (const float*)d_in[7];
    float* out = (float*)d_out;

    char* ws = (char*)d_ws;
    f16_t* x16    = (f16_t*)(ws);
    f16_t* wqkvT  = (f16_t*)(ws + 16777216);
    f16_t* woT    = (f16_t*)(ws + 41943040);
    f16_t* qkv16  = (f16_t*)(ws + 50331648);
    f16_t* attn16 = (f16_t*)(ws + 100663296);

    hipFuncSetAttribute((const void*)&gemm_v4<256, 384, 16, 1>,
                        hipFuncAttributeMaxDynamicSharedMemorySize, 122880);
    hipFuncSetAttribute((const void*)&gemm_v4<128, 256, 32, 0>,
                        hipFuncAttributeMaxDynamicSharedMemorySize, 73728);
    hipFuncSetAttribute((const void*)&attn_f16,
                        hipFuncAttributeMaxDynamicSharedMemorySize, 69632);

    // merged conv + both weight transposes (one dispatch)
    prep<<<20480, 256, 0, stream>>>(x, x16, w_qkv, wqkvT, w_o, woT);

    // qkv = x @ w_qkv: tiles 256x384, grid 16x16=256 (1 round)
    gemm_v4<256, 384, 16, 1><<<256, 512, 122880, stream>>>(x16, wqkvT, qkv16,
                                                           4096, 6144, 2048);

    rmsrope_f16<<<32768, 256, 0, stream>>>(qkv16, pe, q_scale, q_bias, k_scale, k_bias);

    // attention: 68 KB dynamic LDS, 2 blocks/CU, grid 512 = exactly 1 round
    attn_f16<<<512, 256, 69632, stream>>>(qkv16, attn16);

    // out = attn @ w_o: tiles 128x256, grid 32x8=256 (1 round)
    gemm_v4<128, 256, 32, 0><<<256, 512, 73728, stream>>>(attn16, woT, out,
                                                          4096, 2048, 2048);
}